// Round 7
// baseline (1141.634 us; speedup 1.0000x reference)
//
#include <hip/hip_runtime.h>
#include <hip/hip_bf16.h>

typedef unsigned int uint32_ty;

// Problem constants
#define BB 4
#define SS 512
#define DD 768
#define HH 12
#define DHH 64
#define SDD 30

// ---------------------------------------------------------------------------
// K1: projection GEMM  out = (X @ W + b) * scale   (all f32)
// mode 0: write (B,H,S,DH) layout; mode 1: write (B,H,DH,S) (k transposed)
// ---------------------------------------------------------------------------
#define TM 64
#define TN 64
#define TK 16

__global__ void gemm_proj(const float* __restrict__ X,
                          const float* __restrict__ W,
                          const float* __restrict__ bias,
                          float* __restrict__ out, float scale, int mode)
{
    __shared__ float As[TM][TK + 1];
    __shared__ float Bs[TK][TN + 1];
    int tx = threadIdx.x, ty = threadIdx.y;
    int tid = ty * 16 + tx;
    int m0 = blockIdx.y * TM;
    int n0 = blockIdx.x * TN;
    float acc[4][4] = {};
    for (int k0 = 0; k0 < DD; k0 += TK) {
        {
            int r = tid >> 2;            // 0..63
            int kb = (tid & 3) * 4;      // 0,4,8,12
            float4 xv = *(const float4*)(X + (size_t)(m0 + r) * DD + k0 + kb);
            As[r][kb + 0] = xv.x; As[r][kb + 1] = xv.y;
            As[r][kb + 2] = xv.z; As[r][kb + 3] = xv.w;
        }
        {
            int r = tid >> 4;            // 0..15
            int nb = (tid & 15) * 4;     // 0..60
            float4 wv = *(const float4*)(W + (size_t)(k0 + r) * DD + n0 + nb);
            Bs[r][nb + 0] = wv.x; Bs[r][nb + 1] = wv.y;
            Bs[r][nb + 2] = wv.z; Bs[r][nb + 3] = wv.w;
        }
        __syncthreads();
#pragma unroll
        for (int kk = 0; kk < TK; kk++) {
            float a[4], bv[4];
#pragma unroll
            for (int i = 0; i < 4; i++) a[i] = As[ty * 4 + i][kk];
#pragma unroll
            for (int j = 0; j < 4; j++) bv[j] = Bs[kk][tx * 4 + j];
#pragma unroll
            for (int i = 0; i < 4; i++)
#pragma unroll
                for (int j = 0; j < 4; j++) acc[i][j] += a[i] * bv[j];
        }
        __syncthreads();
    }
#pragma unroll
    for (int i = 0; i < 4; i++) {
        int m = m0 + ty * 4 + i;
        int b = m >> 9, s = m & 511;
#pragma unroll
        for (int j = 0; j < 4; j++) {
            int n = n0 + tx * 4 + j;
            int h = n >> 6, d = n & 63;
            float val = (acc[i][j] + bias[n]) * scale;
            size_t idx;
            if (mode == 1)
                idx = ((((size_t)b * HH + h) * DHH + d) * SS + s);
            else
                idx = ((((size_t)b * HH + h) * SS + s) * DHH + d);
            out[idx] = val;
        }
    }
}

// ---------------------------------------------------------------------------
// K3: output GEMM  out = ctx @ Wo + bo  (all f32, f32 OUTPUT)
// ---------------------------------------------------------------------------
__global__ void gemm_out(const float* __restrict__ Xf,
                         const float* __restrict__ W,
                         const float* __restrict__ bias,
                         float* __restrict__ out)
{
    __shared__ float As[TM][TK + 1];
    __shared__ float Bs[TK][TN + 1];
    int tx = threadIdx.x, ty = threadIdx.y;
    int tid = ty * 16 + tx;
    int m0 = blockIdx.y * TM;
    int n0 = blockIdx.x * TN;
    float acc[4][4] = {};
    for (int k0 = 0; k0 < DD; k0 += TK) {
        {
            int r = tid >> 2;
            int kb = (tid & 3) * 4;
            float4 xv = *(const float4*)(Xf + (size_t)(m0 + r) * DD + k0 + kb);
            As[r][kb + 0] = xv.x; As[r][kb + 1] = xv.y;
            As[r][kb + 2] = xv.z; As[r][kb + 3] = xv.w;
        }
        {
            int r = tid >> 4;
            int nb = (tid & 15) * 4;
            float4 wv = *(const float4*)(W + (size_t)(k0 + r) * DD + n0 + nb);
            Bs[r][nb + 0] = wv.x; Bs[r][nb + 1] = wv.y;
            Bs[r][nb + 2] = wv.z; Bs[r][nb + 3] = wv.w;
        }
        __syncthreads();
#pragma unroll
        for (int kk = 0; kk < TK; kk++) {
            float a[4], bv[4];
#pragma unroll
            for (int i = 0; i < 4; i++) a[i] = As[ty * 4 + i][kk];
#pragma unroll
            for (int j = 0; j < 4; j++) bv[j] = Bs[kk][tx * 4 + j];
#pragma unroll
            for (int i = 0; i < 4; i++)
#pragma unroll
                for (int j = 0; j < 4; j++) acc[i][j] += a[i] * bv[j];
        }
        __syncthreads();
    }
#pragma unroll
    for (int i = 0; i < 4; i++) {
        int m = m0 + ty * 4 + i;
#pragma unroll
        for (int j = 0; j < 4; j++) {
            int n = n0 + tx * 4 + j;
            out[(size_t)m * DD + n] = acc[i][j] + bias[n];
        }
    }
}

// ---------------------------------------------------------------------------
// K2 (fused): per (b,q) block — qt/qb, scores (all 12 heads), softmax,
// astr = attn @ structure, ctx = attn@v + astr@Wsv + bsv.
// attn never hits global memory. 256 threads. f32 outputs.
// ---------------------------------------------------------------------------
__global__ __launch_bounds__(256) void attn_fused(
    const float* __restrict__ q,    // (B,H,S,DH)
    const float* __restrict__ kT,   // (B,H,DH,S)
    const float* __restrict__ v,    // (B,H,S,DH)
    const float* __restrict__ structure, // (B,S,S,30) f32
    const int* __restrict__ mask,   // (B,S,S) int32 0/1
    const float* __restrict__ Wsk,  // (30,64)
    const float* __restrict__ bsk,  // (64)
    const float* __restrict__ Wsv,  // (30,64)
    const float* __restrict__ bsv,  // (64)
    float* __restrict__ ctx,        // (B,S,D)
    float* __restrict__ top_attn)   // (B,S,S) f32 OUTPUT
{
    __shared__ float qs[HH][DHH];
    __shared__ float sc[HH][SS];
    __shared__ unsigned short st[SS * SDD];  // structure row as bf16 (30,720 B)
    __shared__ float qt_s[HH][SDD];
    __shared__ float qb_s[HH];
    __shared__ float astr_s[HH][SDD];
    __shared__ float red[256];

    int tid = threadIdx.x;
    int b = blockIdx.x >> 9;
    int qp = blockIdx.x & 511;

    // --- load q rows for all heads ---
    for (int i = tid; i < HH * DHH; i += 256) {
        int h = i >> 6, d = i & 63;
        qs[h][d] = q[(((size_t)b * HH + h) * SS + qp) * DHH + d];
    }
    // --- load structure row (b,qp,:,:) : 512x30 f32 -> bf16 in LDS ---
    {
        const float* sp = structure + ((size_t)b * SS + qp) * (size_t)(SS * SDD);
        for (int i = tid; i < SS * SDD; i += 256)
            st[i] = __bfloat16_as_ushort(__float2bfloat16(sp[i]));
    }
    __syncthreads();

    // --- qt[h][si] = sum_d qs[h][d] * Wsk[si][d]  (360 entries, strided) ---
    for (int i = tid; i < HH * SDD; i += 256) {
        int h = i / SDD, si = i % SDD;
        float a = 0.f;
#pragma unroll
        for (int d = 0; d < DHH; d++) a += qs[h][d] * Wsk[si * DHH + d];
        qt_s[h][si] = a;
    }
    // --- qb[h] = qs[h] . bsk ---
    if (tid < HH) {
        float a = 0.f;
#pragma unroll
        for (int d = 0; d < DHH; d++) a += qs[tid][d] * bsk[d];
        qb_s[tid] = a;
    }
    __syncthreads();

    // --- scores ---
    for (int kk = tid; kk < SS; kk += 256) {
        int mval = mask[((size_t)b * SS + qp) * SS + kk];
        float stf[SDD];
#pragma unroll
        for (int si = 0; si < SDD; si++)
            stf[si] = __uint_as_float(((uint32_ty)st[kk * SDD + si]) << 16);
        for (int h = 0; h < HH; h++) {
            const float* kp = kT + ((size_t)(b * HH + h) * DHH) * SS + kk;
            float s1 = 0.f;
#pragma unroll
            for (int d = 0; d < DHH; d++) s1 += qs[h][d] * kp[(size_t)d * SS];
            float s2 = 0.f;
#pragma unroll
            for (int si = 0; si < SDD; si++) s2 += qt_s[h][si] * stf[si];
            sc[h][kk] = mval ? -1e18f : (s1 + s2 + qb_s[h]);
        }
    }
    __syncthreads();

    // --- softmax per head, attn written in place into sc ---
    for (int h = 0; h < HH; h++) {
        float m = fmaxf(sc[h][tid], sc[h][tid + 256]);
        red[tid] = m;
        __syncthreads();
        for (int off = 128; off > 0; off >>= 1) {
            if (tid < off) red[tid] = fmaxf(red[tid], red[tid + off]);
            __syncthreads();
        }
        float rowmax = red[0];
        __syncthreads();
        float e0 = __expf(sc[h][tid] - rowmax);
        float e1 = __expf(sc[h][tid + 256] - rowmax);
        red[tid] = e0 + e1;
        __syncthreads();
        for (int off = 128; off > 0; off >>= 1) {
            if (tid < off) red[tid] += red[tid + off];
            __syncthreads();
        }
        float inv = 1.f / red[0];
        __syncthreads();
        float a0 = e0 * inv, a1 = e1 * inv;
        sc[h][tid] = a0;
        sc[h][tid + 256] = a1;
        if (h == 0) {
            size_t ob = ((size_t)b * SS + qp) * SS;
            top_attn[ob + tid] = a0;
            top_attn[ob + tid + 256] = a1;
        }
    }
    __syncthreads();

    // --- astr[h][si] = sum_k attn[h][k] * structure[k][si]  (strided) ---
    for (int i = tid; i < HH * SDD; i += 256) {
        int h = i / SDD, si = i % SDD;
        float a = 0.f;
        for (int k = 0; k < SS; k++)
            a += sc[h][k] * __uint_as_float(((uint32_ty)st[k * SDD + si]) << 16);
        astr_s[h][si] = a;
    }
    __syncthreads();

    // --- ctx[o] = sum_k attn[h][k]*v[b,h,k,d] + sum_si astr[h][si]*Wsv[si][d] + bsv[d]
    for (int r = 0; r < 3; r++) {
        int o = tid + 256 * r;          // 0..767
        int h = o >> 6, d = o & 63;
        const float* vp = v + ((size_t)(b * HH + h) * SS) * DHH + d;
        float acc = 0.f;
#pragma unroll 4
        for (int k = 0; k < SS; k++) acc += sc[h][k] * vp[(size_t)k * DHH];
        float a2 = 0.f;
#pragma unroll
        for (int si = 0; si < SDD; si++) a2 += astr_s[h][si] * Wsv[si * DHH + d];
        acc += a2 + bsv[d];
        ctx[((size_t)b * SS + qp) * DD + o] = acc;
    }
}

// ---------------------------------------------------------------------------
extern "C" void kernel_launch(void* const* d_in, const int* in_sizes, int n_in,
                              void* d_out, int out_size, void* d_ws, size_t ws_size,
                              hipStream_t stream)
{
    const float* key       = (const float*)d_in[0];
    const float* value     = (const float*)d_in[1];
    const float* query     = (const float*)d_in[2];
    const float* structure = (const float*)d_in[3];
    const int*   mask      = (const int*)d_in[4];
    const float* Wq  = (const float*)d_in[5];
    const float* bq  = (const float*)d_in[6];
    const float* Wk  = (const float*)d_in[7];
    const float* bk  = (const float*)d_in[8];
    const float* Wv  = (const float*)d_in[9];
    const float* bv  = (const float*)d_in[10];
    const float* Wsk = (const float*)d_in[11];
    const float* bsk = (const float*)d_in[12];
    const float* Wsv = (const float*)d_in[13];
    const float* bsv = (const float*)d_in[14];
    const float* Wo  = (const float*)d_in[15];
    const float* bo  = (const float*)d_in[16];

    // Reference outputs are float32 -> d_out is float32.
    float* out_main = (float*)d_out;                         // (B,S,D)
    float* out_attn = (float*)d_out + (size_t)BB * SS * DD;  // (B,S,S)

    // Workspace: 4 f32 buffers, total 6,291,456 floats = 24 MiB
    float* ws = (float*)d_ws;
    float* q_buf   = ws;                  // (B,H,S,DH)  1,572,864
    float* kT_buf  = ws + 1572864;        // (B,H,DH,S)  1,572,864
    float* v_buf   = ws + 3145728;        // (B,H,S,DH)  1,572,864
    float* ctx_buf = ws + 4718592;        // (B,S,D)     1,572,864

    dim3 gblk(16, 16);
    dim3 ggrd(DD / TN, (BB * SS) / TM);
    const float qscale = 0.125f; // 1/sqrt(64)

    gemm_proj<<<ggrd, gblk, 0, stream>>>(query, Wq, bq, q_buf, qscale, 0);
    gemm_proj<<<ggrd, gblk, 0, stream>>>(key,   Wk, bk, kT_buf, 1.0f,  1);
    gemm_proj<<<ggrd, gblk, 0, stream>>>(value, Wv, bv, v_buf,  1.0f,  0);

    attn_fused<<<BB * SS, 256, 0, stream>>>(q_buf, kT_buf, v_buf, structure, mask,
                                            Wsk, bsk, Wsv, bsv, ctx_buf, out_attn);

    gemm_out<<<ggrd, gblk, 0, stream>>>(ctx_buf, Wo, bo, out_main);
}

// Round 8
// 845.739 us; speedup vs baseline: 1.3499x; 1.3499x over previous
//
#include <hip/hip_runtime.h>
#include <hip/hip_bf16.h>

typedef unsigned int uint32_ty;

// Problem constants
#define BB 4
#define SS 512
#define DD 768
#define HH 12
#define DHH 64
#define SDD 30

__device__ __forceinline__ float bfu(unsigned short u) {
    return __uint_as_float(((uint32_ty)u) << 16);
}
__device__ __forceinline__ unsigned short tobf(float f) {
    return __bfloat16_as_ushort(__float2bfloat16(f));
}

// ---------------------------------------------------------------------------
// K1: fused projection GEMMs.  blockIdx.z selects {query,key,value}.
// out = (X @ W + b) * scale ; z=0 -> q (B,H,S,DH); z=1 -> kT (B,H,DH,S);
// z=2 -> v (B,H,S,DH).
// A-tile stored transposed [k][m] so fragments are ds_read_b128.
// ---------------------------------------------------------------------------
#define TM 64
#define TN 64
#define TKK 32

__global__ __launch_bounds__(256) void gemm_proj3(
    const float* __restrict__ Xq, const float* __restrict__ Xk, const float* __restrict__ Xv,
    const float* __restrict__ Wq, const float* __restrict__ Wk, const float* __restrict__ Wv,
    const float* __restrict__ bq, const float* __restrict__ bk, const float* __restrict__ bv,
    float* __restrict__ oq, float* __restrict__ okT, float* __restrict__ ov)
{
    __shared__ float As[TKK][TM + 4];
    __shared__ float Bs[TKK][TN + 4];
    int z = blockIdx.z;
    const float* X = (z == 0) ? Xq : (z == 1) ? Xk : Xv;
    const float* W = (z == 0) ? Wq : (z == 1) ? Wk : Wv;
    const float* bias = (z == 0) ? bq : (z == 1) ? bk : bv;
    float* out = (z == 0) ? oq : (z == 1) ? okT : ov;
    const float scale = (z == 0) ? 0.125f : 1.0f;

    int tx = threadIdx.x, ty = threadIdx.y;
    int tid = ty * 16 + tx;
    int m0 = blockIdx.y * TM;
    int n0 = blockIdx.x * TN;
    float acc[4][4] = {};
    for (int k0 = 0; k0 < DD; k0 += TKK) {
#pragma unroll
        for (int rep = 0; rep < 2; rep++) {
            int f = tid + 256 * rep;
            int r = f >> 3;          // 0..63 row (m)
            int c = f & 7;           // float4 col -> k = 4c
            float4 xv = *(const float4*)(X + (size_t)(m0 + r) * DD + k0 + 4 * c);
            As[4 * c + 0][r] = xv.x; As[4 * c + 1][r] = xv.y;
            As[4 * c + 2][r] = xv.z; As[4 * c + 3][r] = xv.w;
        }
#pragma unroll
        for (int rep = 0; rep < 2; rep++) {
            int f = tid + 256 * rep;
            int r = f >> 4;          // 0..31 k-row
            int c = f & 15;          // float4 col -> n = 4c
            float4 wv = *(const float4*)(W + (size_t)(k0 + r) * DD + n0 + 4 * c);
            *(float4*)&Bs[r][4 * c] = wv;
        }
        __syncthreads();
#pragma unroll 8
        for (int kk = 0; kk < TKK; kk++) {
            float4 av = *(float4*)&As[kk][ty * 4];
            float4 bv4 = *(float4*)&Bs[kk][tx * 4];
            float a[4] = {av.x, av.y, av.z, av.w};
            float bb[4] = {bv4.x, bv4.y, bv4.z, bv4.w};
#pragma unroll
            for (int i = 0; i < 4; i++)
#pragma unroll
                for (int j = 0; j < 4; j++) acc[i][j] += a[i] * bb[j];
        }
        __syncthreads();
    }
#pragma unroll
    for (int i = 0; i < 4; i++) {
        int m = m0 + ty * 4 + i;
        int b = m >> 9, s = m & 511;
#pragma unroll
        for (int j = 0; j < 4; j++) {
            int n = n0 + tx * 4 + j;
            int h = n >> 6, d = n & 63;
            float val = (acc[i][j] + bias[n]) * scale;
            size_t idx;
            if (z == 1)
                idx = ((((size_t)b * HH + h) * DHH + d) * SS + s);
            else
                idx = ((((size_t)b * HH + h) * SS + s) * DHH + d);
            out[idx] = val;
        }
    }
}

// ---------------------------------------------------------------------------
// K3: output GEMM  out = ctx @ Wo + bo  (all f32, f32 out)
// ---------------------------------------------------------------------------
__global__ __launch_bounds__(256) void gemm_out(
    const float* __restrict__ Xf, const float* __restrict__ W,
    const float* __restrict__ bias, float* __restrict__ out)
{
    __shared__ float As[TKK][TM + 4];
    __shared__ float Bs[TKK][TN + 4];
    int tx = threadIdx.x, ty = threadIdx.y;
    int tid = ty * 16 + tx;
    int m0 = blockIdx.y * TM;
    int n0 = blockIdx.x * TN;
    float acc[4][4] = {};
    for (int k0 = 0; k0 < DD; k0 += TKK) {
#pragma unroll
        for (int rep = 0; rep < 2; rep++) {
            int f = tid + 256 * rep;
            int r = f >> 3, c = f & 7;
            float4 xv = *(const float4*)(Xf + (size_t)(m0 + r) * DD + k0 + 4 * c);
            As[4 * c + 0][r] = xv.x; As[4 * c + 1][r] = xv.y;
            As[4 * c + 2][r] = xv.z; As[4 * c + 3][r] = xv.w;
        }
#pragma unroll
        for (int rep = 0; rep < 2; rep++) {
            int f = tid + 256 * rep;
            int r = f >> 4, c = f & 15;
            float4 wv = *(const float4*)(W + (size_t)(k0 + r) * DD + n0 + 4 * c);
            *(float4*)&Bs[r][4 * c] = wv;
        }
        __syncthreads();
#pragma unroll 8
        for (int kk = 0; kk < TKK; kk++) {
            float4 av = *(float4*)&As[kk][ty * 4];
            float4 bv4 = *(float4*)&Bs[kk][tx * 4];
            float a[4] = {av.x, av.y, av.z, av.w};
            float bb[4] = {bv4.x, bv4.y, bv4.z, bv4.w};
#pragma unroll
            for (int i = 0; i < 4; i++)
#pragma unroll
                for (int j = 0; j < 4; j++) acc[i][j] += a[i] * bb[j];
        }
        __syncthreads();
    }
#pragma unroll
    for (int i = 0; i < 4; i++) {
        int m = m0 + ty * 4 + i;
#pragma unroll
        for (int j = 0; j < 4; j++) {
            int n = n0 + tx * 4 + j;
            out[(size_t)m * DD + n] = acc[i][j] + bias[n];
        }
    }
}

// ---------------------------------------------------------------------------
// K2 (fused attention): per (b,q) block, 256 threads = 4 waves.
// Wave w owns heads 3w..3w+2; softmax entirely in registers + shuffles.
// LDS 49,008 B -> 3 blocks/CU.
// ---------------------------------------------------------------------------
__global__ __launch_bounds__(256) void attn_fused(
    const float* __restrict__ q,    // (B,H,S,DH)
    const float* __restrict__ kT,   // (B,H,DH,S)
    const float* __restrict__ v,    // (B,H,S,DH)
    const float* __restrict__ structure, // (B,S,S,30) f32
    const int* __restrict__ mask,   // (B,S,S) int32 0/1
    const float* __restrict__ Wsk,  // (30,64)
    const float* __restrict__ bsk,  // (64)
    const float* __restrict__ Wsv,  // (30,64)
    const float* __restrict__ bsv,  // (64)
    float* __restrict__ ctx,        // (B,S,D)
    float* __restrict__ top_attn)   // (B,S,S) f32
{
    __shared__ float qs[HH][DHH];            //  3072 B
    __shared__ unsigned short st[SS * SDD];  // 30720 B  structure row bf16
    __shared__ float qt_s[HH][SDD];          //  1440 B
    __shared__ float qb_s[HH];               //    48 B
    __shared__ float astr_s[HH][SDD];        //  1440 B
    __shared__ unsigned short at[SS][HH];    // 12288 B  attn bf16 [k][h]

    int tid = threadIdx.x;
    int lane = tid & 63, wave = tid >> 6;
    int b = blockIdx.x >> 9;
    int qp = blockIdx.x & 511;

    // --- load q rows for all heads ---
    for (int i = tid; i < HH * DHH; i += 256) {
        int h = i >> 6, d = i & 63;
        qs[h][d] = q[(((size_t)b * HH + h) * SS + qp) * DHH + d];
    }
    // --- load structure row (b,qp,:,:) f32 -> bf16 LDS, vectorized ---
    {
        const float4* sp = (const float4*)(structure + ((size_t)b * SS + qp) * (size_t)(SS * SDD));
        for (int i = tid; i < SS * SDD / 4; i += 256) {
            float4 xv = sp[i];
            uint32_ty u0 = (uint32_ty)tobf(xv.x) | ((uint32_ty)tobf(xv.y) << 16);
            uint32_ty u1 = (uint32_ty)tobf(xv.z) | ((uint32_ty)tobf(xv.w) << 16);
            uint2 pk; pk.x = u0; pk.y = u1;
            *(uint2*)&st[4 * i] = pk;
        }
    }
    __syncthreads();

    // --- qt[h][si] = qs[h] . Wsk[si]; qb[h] = qs[h] . bsk ---
    for (int i = tid; i < HH * SDD; i += 256) {
        int h = i / SDD, si = i % SDD;
        float a = 0.f;
#pragma unroll
        for (int d = 0; d < DHH; d++) a += qs[h][d] * Wsk[si * DHH + d];
        qt_s[h][si] = a;
    }
    if (tid < HH) {
        float a = 0.f;
#pragma unroll
        for (int d = 0; d < DHH; d++) a += qs[tid][d] * bsk[d];
        qb_s[tid] = a;
    }
    __syncthreads();

    // --- scores in registers: wave w -> heads 3w..3w+2, lane owns kk=lane+64j ---
    int h0 = wave * 3;
    float attnv[3][8];
    const int* mrow = mask + ((size_t)b * SS + qp) * SS;
    for (int j = 0; j < 8; j++) {
        int kk = lane + 64 * j;
        int mval = mrow[kk];
        // structure-score term, dword-packed bf16 reads (15 dwords/row)
        float s2[3] = {0.f, 0.f, 0.f};
        const uint32_ty* stp32 = (const uint32_ty*)&st[kk * SDD];
#pragma unroll
        for (int w = 0; w < 15; w++) {
            uint32_ty u = stp32[w];
            float f0 = __uint_as_float(u << 16);
            float f1 = __uint_as_float(u & 0xFFFF0000u);
#pragma unroll
            for (int h = 0; h < 3; h++) {
                s2[h] += qt_s[h0 + h][2 * w] * f0;
                s2[h] += qt_s[h0 + h][2 * w + 1] * f1;
            }
        }
#pragma unroll
        for (int h = 0; h < 3; h++) {
            const float* kp = kT + (((size_t)b * HH + h0 + h) * DHH) * SS + kk;
            float s1a = 0.f, s1b = 0.f;
#pragma unroll 8
            for (int d = 0; d < DHH; d += 2) {
                s1a += qs[h0 + h][d] * kp[(size_t)d * SS];
                s1b += qs[h0 + h][d + 1] * kp[(size_t)(d + 1) * SS];
            }
            float sv = s1a + s1b + s2[h] + qb_s[h0 + h];
            attnv[h][j] = mval ? -1e18f : sv;
        }
    }

    // --- softmax per head, in-wave (no barriers) ---
#pragma unroll
    for (int h = 0; h < 3; h++) {
        float m = attnv[h][0];
#pragma unroll
        for (int j = 1; j < 8; j++) m = fmaxf(m, attnv[h][j]);
#pragma unroll
        for (int off = 32; off > 0; off >>= 1) m = fmaxf(m, __shfl_xor(m, off));
        float l = 0.f;
#pragma unroll
        for (int j = 0; j < 8; j++) { attnv[h][j] = __expf(attnv[h][j] - m); l += attnv[h][j]; }
#pragma unroll
        for (int off = 32; off > 0; off >>= 1) l += __shfl_xor(l, off);
        float inv = 1.f / l;
#pragma unroll
        for (int j = 0; j < 8; j++) {
            float a = attnv[h][j] * inv;
            int kk = lane + 64 * j;
            at[kk][h0 + h] = tobf(a);
            if (h0 + h == 0) top_attn[((size_t)b * SS + qp) * SS + kk] = a;
        }
    }
    __syncthreads();

    // --- astr[h][si] = sum_k attn[h][k] * structure[k][si] ---
    for (int i = tid; i < HH * SDD; i += 256) {
        int h = i / SDD, si = i % SDD;
        float a0 = 0.f, a1 = 0.f;
        for (int k = 0; k < SS; k += 2) {
            a0 += bfu(at[k][h]) * bfu(st[k * SDD + si]);
            a1 += bfu(at[k + 1][h]) * bfu(st[(k + 1) * SDD + si]);
        }
        astr_s[h][si] = a0 + a1;
    }
    __syncthreads();

    // --- ctx[o] = attn@v + astr@Wsv + bsv ---
#pragma unroll
    for (int r = 0; r < 3; r++) {
        int o = tid + 256 * r;          // 0..767
        int h = o >> 6, d = o & 63;
        const float* vp = v + ((size_t)(b * HH + h) * SS) * DHH + d;
        float acc0 = 0.f, acc1 = 0.f;
#pragma unroll 4
        for (int k = 0; k < SS; k += 2) {
            acc0 += bfu(at[k][h]) * vp[(size_t)k * DHH];
            acc1 += bfu(at[k + 1][h]) * vp[(size_t)(k + 1) * DHH];
        }
        float a2 = 0.f;
#pragma unroll
        for (int si = 0; si < SDD; si++) a2 += astr_s[h][si] * Wsv[si * DHH + d];
        ctx[((size_t)b * SS + qp) * DD + o] = acc0 + acc1 + a2 + bsv[d];
    }
}

// ---------------------------------------------------------------------------
extern "C" void kernel_launch(void* const* d_in, const int* in_sizes, int n_in,
                              void* d_out, int out_size, void* d_ws, size_t ws_size,
                              hipStream_t stream)
{
    const float* key       = (const float*)d_in[0];
    const float* value     = (const float*)d_in[1];
    const float* query     = (const float*)d_in[2];
    const float* structure = (const float*)d_in[3];
    const int*   mask      = (const int*)d_in[4];
    const float* Wq  = (const float*)d_in[5];
    const float* bq  = (const float*)d_in[6];
    const float* Wk  = (const float*)d_in[7];
    const float* bk  = (const float*)d_in[8];
    const float* Wv  = (const float*)d_in[9];
    const float* bv  = (const float*)d_in[10];
    const float* Wsk = (const float*)d_in[11];
    const float* bsk = (const float*)d_in[12];
    const float* Wsv = (const float*)d_in[13];
    const float* bsv = (const float*)d_in[14];
    const float* Wo  = (const float*)d_in[15];
    const float* bo  = (const float*)d_in[16];

    float* out_main = (float*)d_out;                         // (B,S,D)
    float* out_attn = (float*)d_out + (size_t)BB * SS * DD;  // (B,S,S)

    float* ws = (float*)d_ws;
    float* q_buf   = ws;                  // (B,H,S,DH)  1,572,864
    float* kT_buf  = ws + 1572864;        // (B,H,DH,S)  1,572,864
    float* v_buf   = ws + 3145728;        // (B,H,S,DH)  1,572,864
    float* ctx_buf = ws + 4718592;        // (B,S,D)     1,572,864

    dim3 gblk(16, 16);
    dim3 ggrd3(DD / TN, (BB * SS) / TM, 3);
    dim3 ggrd(DD / TN, (BB * SS) / TM);

    gemm_proj3<<<ggrd3, gblk, 0, stream>>>(query, key, value, Wq, Wk, Wv,
                                           bq, bk, bv, q_buf, kT_buf, v_buf);

    attn_fused<<<BB * SS, 256, 0, stream>>>(q_buf, kT_buf, v_buf, structure, mask,
                                            Wsk, bsk, Wsv, bsv, ctx_buf, out_attn);

    gemm_out<<<ggrd, gblk, 0, stream>>>(ctx_buf, Wo, bo, out_main);
}